// Round 1
// 383.265 us; speedup vs baseline: 1.0654x; 1.0654x over previous
//
#include <hip/hip_runtime.h>
#include <hip/hip_bf16.h>

#define FEAT 128
#define NRELS 8
#define SCAN_CHUNK 256
#define GT 64   // GEMM node tile

typedef __bf16 bf16_t;
typedef __bf16 bf16x2_t __attribute__((ext_vector_type(2)));
typedef __bf16 bf16x4_t __attribute__((ext_vector_type(4)));
typedef __bf16 bf16x8_t __attribute__((ext_vector_type(8)));
typedef float f32x4 __attribute__((ext_vector_type(4)));

struct __align__(8) PackedEdge { int row; float scale; };

static inline size_t align256(size_t x) { return (x + 255) & ~(size_t)255; }

// ---------------------------------------------------------------------------
// Weight [R][d][f] fp32 -> Wt [R][f][d] bf16 (transposed: MFMA A-fragments need
// contiguous k=d per lane -> 16B vector loads).
__global__ void k_convert_w(const float* __restrict__ w, bf16_t* __restrict__ wt) {
    int i = blockIdx.x * blockDim.x + threadIdx.x;
    if (i >= NRELS * FEAT * FEAT) return;
    int r = i >> 14;
    int rem = i & 16383;
    int d = rem >> 7;
    int f = rem & 127;
    wt[(r << 14) + (f << 7) + d] = (bf16_t)w[i];
}

// ---------------------------------------------------------------------------
// Gate: sg[n][r] = sigmoid(sum_d h[n][d]*gw[r][d]); fp32. One wave per node.
__global__ void k_gate(const float* __restrict__ h, const float* __restrict__ gw,
                       float* __restrict__ sg, int node0, int ncount) {
    int wv = (int)((blockIdx.x * blockDim.x + threadIdx.x) >> 6);
    int lane = threadIdx.x & 63;
    if (wv >= ncount) return;
    float2 hv = *reinterpret_cast<const float2*>(h + (size_t)(node0 + wv) * FEAT + lane * 2);
    float res[NRELS];
#pragma unroll
    for (int r = 0; r < NRELS; ++r) {
        float2 wvv = *reinterpret_cast<const float2*>(gw + r * FEAT + lane * 2);
        float s = hv.x * wvv.x + hv.y * wvv.y;
#pragma unroll
        for (int off = 32; off; off >>= 1) s += __shfl_xor(s, off, 64);
        res[r] = s;
    }
    if (lane == 0) {
#pragma unroll
        for (int r = 0; r < NRELS; ++r)
            sg[(size_t)wv * NRELS + r] = 1.0f / (1.0f + __expf(-res[r]));
    }
}

// ---------------------------------------------------------------------------
// GEMM, all 8 relations per block. Block = 4 waves = one 64-node tile.
// Reads h fp32 directly (in-register bf16 convert; no hb pass). Gate sigmoid
// folded into the stored hall values. hall layout [R][Nceil][F]: per relation
// the block's 64x128 tile is a CONTIGUOUS 16KB region -> after an LDS
// transpose each wave stores 64 lanes x 16B = contiguous 1KB.
// LDS is XOR-swizzled at 16B-chunk granularity (chunk ^ (node&15)) so both the
// acc-layout writes and the row-major reads stay ~conflict-free.
__global__ __launch_bounds__(256, 2) void k_gemm8(const float* __restrict__ h,
                                                  const bf16_t* __restrict__ wt,
                                                  const float* __restrict__ sg,
                                                  bf16_t* __restrict__ hall,
                                                  int nvalid, int planeElems) {
    __shared__ __align__(16) bf16_t lds[2][GT * FEAT];
    const int tile = blockIdx.x;
    const int t = threadIdx.x;
    const int wv = t >> 6;
    const int lane = t & 63;
    const int l15 = lane & 15;
    const int lhi = lane >> 4;
    const int f_base = wv * 32;        // wave covers f in [f_base, f_base+32)
    const int node_base = tile * GT;

    // B-fragments: B[k][n], n = tn*16 + l15, k = ks*32 + lhi*8 + j
    bf16x8_t bfrag[4][4];
#pragma unroll
    for (int tn = 0; tn < 4; ++tn) {
        int node = node_base + tn * 16 + l15;
        const float* hp = h + (size_t)node * FEAT + lhi * 8;
        bool valid = node < nvalid;
#pragma unroll
        for (int ks = 0; ks < 4; ++ks) {
            bf16x8_t o;
            if (valid) {
                float4 v0 = reinterpret_cast<const float4*>(hp + ks * 32)[0];
                float4 v1 = reinterpret_cast<const float4*>(hp + ks * 32)[1];
                o[0] = (bf16_t)v0.x; o[1] = (bf16_t)v0.y;
                o[2] = (bf16_t)v0.z; o[3] = (bf16_t)v0.w;
                o[4] = (bf16_t)v1.x; o[5] = (bf16_t)v1.y;
                o[6] = (bf16_t)v1.z; o[7] = (bf16_t)v1.w;
            } else {
#pragma unroll
                for (int i = 0; i < 8; ++i) o[i] = (bf16_t)0.f;
            }
            bfrag[tn][ks] = o;
        }
    }

#pragma unroll 1
    for (int r = 0; r < NRELS; ++r) {
        // A-fragments from Wt[r]: A[m=f][k], k contiguous per lane (L2-hot)
        bf16x8_t afrag[2][4];
#pragma unroll
        for (int tm = 0; tm < 2; ++tm) {
            const bf16_t* ap = wt + ((size_t)r << 14) +
                               (size_t)(f_base + tm * 16 + l15) * FEAT + lhi * 8;
#pragma unroll
            for (int ks = 0; ks < 4; ++ks)
                afrag[tm][ks] = *reinterpret_cast<const bf16x8_t*>(ap + ks * 32);
        }
        // Gate values for this wave's node columns (L2-resident sg)
        float g[4];
#pragma unroll
        for (int tn = 0; tn < 4; ++tn) {
            int node = node_base + tn * 16 + l15;
            g[tn] = (node < nvalid) ? sg[(size_t)node * NRELS + r] : 0.f;
        }

        f32x4 acc[2][4];
#pragma unroll
        for (int tm = 0; tm < 2; ++tm)
#pragma unroll
            for (int tn = 0; tn < 4; ++tn)
                acc[tm][tn] = (f32x4){0.f, 0.f, 0.f, 0.f};

#pragma unroll
        for (int ks = 0; ks < 4; ++ks)
#pragma unroll
            for (int tn = 0; tn < 4; ++tn)
#pragma unroll
                for (int tm = 0; tm < 2; ++tm)
                    acc[tm][tn] = __builtin_amdgcn_mfma_f32_16x16x32_bf16(
                        afrag[tm][ks], bfrag[tn][ks], acc[tm][tn], 0, 0, 0);

        // Scale by gate, convert, stage into LDS (swizzled).
        // C layout: col(l15)=node, row(lhi*4+i)=f  (m89-verified)
        bf16_t* buf = lds[r & 1];
#pragma unroll
        for (int tm = 0; tm < 2; ++tm) {
            int f0 = f_base + tm * 16 + lhi * 4;
#pragma unroll
            for (int tn = 0; tn < 4; ++tn) {
                int node = tn * 16 + l15;
                bf16x4_t o;
                o.x = (bf16_t)(acc[tm][tn][0] * g[tn]);
                o.y = (bf16_t)(acc[tm][tn][1] * g[tn]);
                o.z = (bf16_t)(acc[tm][tn][2] * g[tn]);
                o.w = (bf16_t)(acc[tm][tn][3] * g[tn]);
                int idx = node * FEAT + ((((f0 >> 3) ^ node) & 15) << 3) + (f0 & 7);
                *reinterpret_cast<bf16x4_t*>(&buf[idx]) = o;
            }
        }
        __syncthreads();   // single barrier per r; LDS double-buffer covers WAR

        // Coalesced store: per wave, 4 consecutive node rows x 16 chunks = 1KB
        bf16_t* plane = hall + (size_t)r * planeElems;
#pragma unroll
        for (int it = 0; it < 4; ++it) {
            int node = it * 16 + (t >> 4);
            int sub = t & 15;
            bf16x8_t v = *reinterpret_cast<const bf16x8_t*>(
                &buf[node * FEAT + (((sub ^ node) & 15) << 3)]);
            *reinterpret_cast<bf16x8_t*>(
                plane + (size_t)(node_base + node) * FEAT + sub * 8) = v;
        }
    }
}

// ---------------------------------------------------------------------------
// CSR build
__global__ void k_degree(const int* __restrict__ dstv, int* __restrict__ deg, int nedges) {
    int e = blockIdx.x * blockDim.x + threadIdx.x;
    if (e >= nedges) return;
    atomicAdd(&deg[dstv[e]], 1);
}

__global__ __launch_bounds__(256) void k_scan_block(const int* __restrict__ in,
                                                    int* __restrict__ outv,
                                                    int* __restrict__ bsum, int n) {
    __shared__ int sm[256];
    int t = threadIdx.x;
    int idx = blockIdx.x * SCAN_CHUNK + t;
    int v = (idx < n) ? in[idx] : 0;
    sm[t] = v;
    __syncthreads();
    for (int off = 1; off < 256; off <<= 1) {
        int x = (t >= off) ? sm[t - off] : 0;
        __syncthreads();
        sm[t] += x;
        __syncthreads();
    }
    if (idx < n) outv[idx] = sm[t] - v;
    if (t == 255) bsum[blockIdx.x] = sm[255];
}

__global__ __launch_bounds__(1024) void k_scan_tops(int* __restrict__ bsum, int nb,
                                                    int* __restrict__ rowptr_end) {
    __shared__ int sm[1024];
    int t = threadIdx.x;
    if (nb <= 1024) {
        int v = (t < nb) ? bsum[t] : 0;
        sm[t] = v;
        __syncthreads();
        for (int off = 1; off < 1024; off <<= 1) {
            int x = (t >= off) ? sm[t - off] : 0;
            __syncthreads();
            sm[t] += x;
            __syncthreads();
        }
        if (t < nb) bsum[t] = sm[t] - v;
        if (t == 1023) *rowptr_end = sm[1023];
    } else if (t == 0) {
        int run = 0;
        for (int b = 0; b < nb; ++b) { int v = bsum[b]; bsum[b] = run; run += v; }
        *rowptr_end = run;
    }
}

__global__ void k_scan_add(int* __restrict__ rowptr, const int* __restrict__ bsum, int n) {
    int i = blockIdx.x * blockDim.x + threadIdx.x;
    if (i >= n) return;
    rowptr[i] += bsum[i >> 8];   // 256 = 1<<8
}

// Fill packed edge records {hall_row, norm} at CSR slots. Gate is already
// folded into hall, so scale = norm only (no random sg read).
__global__ void k_fill(const int* __restrict__ src, const int* __restrict__ dstv,
                       const int* __restrict__ rel, const float* __restrict__ nrm,
                       const int* __restrict__ rowptr, int* __restrict__ cursor,
                       PackedEdge* __restrict__ packed, int planeRows, int nedges) {
    int e = blockIdx.x * blockDim.x + threadIdx.x;
    if (e >= nedges) return;
    int d = dstv[e];
    int pos = rowptr[d] + atomicAdd(&cursor[d], 1);
    PackedEdge p;
    p.row = rel[e] * planeRows + src[e];
    p.scale = nrm[e];
    packed[pos] = p;
}

// ---------------------------------------------------------------------------
// Gather: one wave per dst node, 4 edges per iteration (16 lanes each:
// 16 lanes x bf16x8 = one 256B hall row). Reduce via shfl_xor(16) + (32).
__global__ __launch_bounds__(256) void k_gather(const bf16_t* __restrict__ hall,
                                                const PackedEdge* __restrict__ packed,
                                                const int* __restrict__ rowptr,
                                                float* __restrict__ out, int nnodes) {
    int wv = (int)((blockIdx.x * blockDim.x + threadIdx.x) >> 6);
    int lane = threadIdx.x & 63;
    if (wv >= nnodes) return;
    int q = lane >> 4;           // edge slot 0..3
    int sub = lane & 15;         // feature group: feats [sub*8, sub*8+8)
    int beg = rowptr[wv];
    int end = rowptr[wv + 1];
    float a[8];
#pragma unroll
    for (int i = 0; i < 8; ++i) a[i] = 0.f;
    int j = beg + q;
    PackedEdge p;
    if (j < end) p = packed[j];
#pragma unroll 1
    for (; j < end; j += 4) {
        PackedEdge pn;
        if (j + 4 < end) pn = packed[j + 4];     // prefetch next record
        bf16x8_t mv = *reinterpret_cast<const bf16x8_t*>(
            hall + (size_t)p.row * FEAT + sub * 8);
        float s = p.scale;
        a[0] += (float)mv[0] * s;
        a[1] += (float)mv[1] * s;
        a[2] += (float)mv[2] * s;
        a[3] += (float)mv[3] * s;
        a[4] += (float)mv[4] * s;
        a[5] += (float)mv[5] * s;
        a[6] += (float)mv[6] * s;
        a[7] += (float)mv[7] * s;
        p = pn;
    }
#pragma unroll
    for (int i = 0; i < 8; ++i) {
        a[i] += __shfl_xor(a[i], 16);
        a[i] += __shfl_xor(a[i], 32);
    }
    if (q == 0) {
        float4 o0, o1;
        o0.x = fmaxf(a[0], 0.f); o0.y = fmaxf(a[1], 0.f);
        o0.z = fmaxf(a[2], 0.f); o0.w = fmaxf(a[3], 0.f);
        o1.x = fmaxf(a[4], 0.f); o1.y = fmaxf(a[5], 0.f);
        o1.z = fmaxf(a[6], 0.f); o1.w = fmaxf(a[7], 0.f);
        float4* op = reinterpret_cast<float4*>(out + (size_t)wv * FEAT + sub * 8);
        op[0] = o0;
        op[1] = o1;
    }
}

// ---------------------------------------------------------------------------
// Fallback path (small ws): chunked atomic scatter. hall layout [R][Cc][F].
__global__ __launch_bounds__(256) void k_scatter(const bf16_t* __restrict__ hall,
                                                 const float* __restrict__ nrm,
                                                 const int* __restrict__ src,
                                                 const int* __restrict__ dstv,
                                                 const int* __restrict__ rel,
                                                 float* __restrict__ out,
                                                 int node0, int ncount, int planeRows,
                                                 int nedges) {
    int e = (int)((blockIdx.x * blockDim.x + threadIdx.x) >> 6);
    if (e >= nedges) return;
    int lane = threadIdx.x & 63;
    int s = src[e] - node0;
    if ((unsigned)s >= (unsigned)ncount) return;
    int r = rel[e];
    float scale = nrm[e];
    bf16x2_t mv = *reinterpret_cast<const bf16x2_t*>(
        hall + (size_t)(r * planeRows + s) * FEAT + lane * 2);
    float* op = out + (size_t)dstv[e] * FEAT + lane * 2;
    unsafeAtomicAdd(op, (float)mv.x * scale);
    unsafeAtomicAdd(op + 1, (float)mv.y * scale);
}

__global__ void k_relu(float4* __restrict__ out, int total4) {
    int i = blockIdx.x * blockDim.x + threadIdx.x;
    if (i >= total4) return;
    float4 v = out[i];
    v.x = fmaxf(v.x, 0.f);
    v.y = fmaxf(v.y, 0.f);
    v.z = fmaxf(v.z, 0.f);
    v.w = fmaxf(v.w, 0.f);
    out[i] = v;
}

// ---------------------------------------------------------------------------
extern "C" void kernel_launch(void* const* d_in, const int* in_sizes, int n_in,
                              void* d_out, int out_size, void* d_ws, size_t ws_size,
                              hipStream_t stream) {
    const float* h = (const float*)d_in[0];
    const float* w = (const float*)d_in[1];
    const float* gw = (const float*)d_in[2];
    const float* nrm = (const float*)d_in[3];
    const int* src = (const int*)d_in[4];
    const int* dst = (const int*)d_in[5];
    const int* rel = (const int*)d_in[6];
    float* out = (float*)d_out;

    const int N = in_sizes[0] / FEAT;
    const int E = in_sizes[4];
    const int Nceil = ((N + GT - 1) / GT) * GT;
    const int nb = (N + SCAN_CHUNK - 1) / SCAN_CHUNK;

    char* ws = (char*)d_ws;
    const size_t wtB = (size_t)NRELS * FEAT * FEAT * sizeof(bf16_t);      // 256 KiB
    const size_t hallB = (size_t)NRELS * Nceil * FEAT * sizeof(bf16_t);   // ~205 MB
    const size_t sgB = align256((size_t)N * NRELS * sizeof(float));
    const size_t degB = align256((size_t)N * sizeof(int));
    const size_t rowB = align256((size_t)(N + 1) * sizeof(int));
    const size_t bsB = align256((size_t)nb * sizeof(int));
    const size_t pkB = align256((size_t)E * sizeof(PackedEdge));
    const size_t csrB = sgB + degB + rowB + bsB + pkB;

    if (wtB + hallB + csrB <= ws_size) {
        // ------------------ full-graph CSR path ------------------
        bf16_t* wt = (bf16_t*)ws;
        bf16_t* hall = (bf16_t*)(ws + wtB);
        char* tail = ws + wtB + hallB;
        float* sg = (float*)tail;
        int* deg = (int*)(tail + sgB);
        int* rowptr = (int*)(tail + sgB + degB);
        int* bsum = (int*)(tail + sgB + degB + rowB);
        PackedEdge* packed = (PackedEdge*)(tail + sgB + degB + rowB + bsB);

        k_convert_w<<<(NRELS * FEAT * FEAT + 255) / 256, 256, 0, stream>>>(w, wt);
        k_gate<<<(N + 3) / 4, 256, 0, stream>>>(h, gw, sg, 0, N);
        k_gemm8<<<Nceil / GT, 256, 0, stream>>>(h, wt, sg, hall, N, Nceil * FEAT);
        hipMemsetAsync(deg, 0, (size_t)N * sizeof(int), stream);
        k_degree<<<(E + 255) / 256, 256, 0, stream>>>(dst, deg, E);
        k_scan_block<<<nb, 256, 0, stream>>>(deg, rowptr, bsum, N);
        k_scan_tops<<<1, 1024, 0, stream>>>(bsum, nb, rowptr + N);
        k_scan_add<<<(N + 255) / 256, 256, 0, stream>>>(rowptr, bsum, N);
        hipMemsetAsync(deg, 0, (size_t)N * sizeof(int), stream);          // reuse as cursor
        k_fill<<<(E + 255) / 256, 256, 0, stream>>>(src, dst, rel, nrm, rowptr, deg,
                                                    packed, Nceil, E);
        k_gather<<<(N + 3) / 4, 256, 0, stream>>>(hall, packed, rowptr, out, N);
    } else {
        // ------------------ chunked atomic fallback ------------------
        bf16_t* wt = (bf16_t*)ws;
        const size_t per_node = NRELS * sizeof(float)
                              + (size_t)NRELS * FEAT * sizeof(bf16_t);
        size_t avail = ws_size > wtB ? ws_size - wtB : 0;
        long long cmax = (long long)(avail / per_node);
        int C = (int)((cmax / GT) * GT);
        if (C > Nceil) C = Nceil;
        if (C < GT) C = GT;
        float* sg = (float*)(ws + wtB);
        bf16_t* hall = (bf16_t*)(ws + wtB + (size_t)C * NRELS * sizeof(float));

        hipMemsetAsync(d_out, 0, (size_t)N * FEAT * sizeof(float), stream);
        k_convert_w<<<(NRELS * FEAT * FEAT + 255) / 256, 256, 0, stream>>>(w, wt);
        for (int node0 = 0; node0 < N; node0 += C) {
            int nc = N - node0;
            if (nc > C) nc = C;
            int ncceil = ((nc + GT - 1) / GT) * GT;
            k_gate<<<(nc + 3) / 4, 256, 0, stream>>>(h, gw, sg, node0, nc);
            k_gemm8<<<ncceil / GT, 256, 0, stream>>>(h + (size_t)node0 * FEAT, wt, sg,
                                                     hall, nc, ncceil * FEAT);
            k_scatter<<<(E + 3) / 4, 256, 0, stream>>>(hall, nrm, src, dst, rel, out,
                                                       node0, nc, ncceil, E);
        }
        k_relu<<<((N * FEAT / 4) + 255) / 256, 256, 0, stream>>>((float4*)out, N * FEAT / 4);
    }
}